// Round 1
// baseline (1080.360 us; speedup 1.0000x reference)
//
#include <hip/hip_runtime.h>
#include <hip/hip_bf16.h>

typedef __bf16 bf16x8 __attribute__((ext_vector_type(8)));
typedef float  f32x4  __attribute__((ext_vector_type(4)));

#define M_TOT 8192
#define N_TOT 4096
#define K_TOT 4096
#define NKB   256     // 16-wide k-blocks
#define NCH   32      // k-chunks (8 k-blocks = 128 k each)
#define CCOLS 1024    // n-columns per workgroup
#define BM    16      // m-rows per workgroup

// Mask storage-width flags, detected on-device each call.
__device__ int g_flags;

// ---------------------------------------------------------------------------
// Detect mask storage width: 1 B (bool/int8), 2 B (bf16/fp16), 4 B (int32/fp32).
// (verbatim from previous passing kernel)
// ---------------------------------------------------------------------------
__global__ void bsl_detect(const unsigned char* __restrict__ mask) {
    __shared__ int sf[256];
    const int t = threadIdx.x;
    int f = 0;
    for (int i = t * 256; i < t * 256 + 256; ++i) {
        unsigned char b = mask[i];
        if (b) {
            if ((i & 1) && b == 1) f |= 1;
            if ((i & 3) == 1 && (b == 0x3F || b == 0x80 || b == 0x3C)) f |= 2;
        }
    }
    sf[t] = f;
    __syncthreads();
    if (t == 0) {
        int acc = 0;
        for (int i = 0; i < 256; ++i) acc |= sf[i];
        g_flags = acc;
    }
}

// ---------------------------------------------------------------------------
// Block-sparse GEMM, restructured for GUARANTEED x reuse.
// Workgroup = 16 m-rows x 1024 n-cols (64 n-blocks). 4 waves, each owns a
// 16-block n-quarter (acc = 16 x f32x4, statically indexed).
// Outer loop: 32 k-chunks (128 k each). Per chunk: x[16][128] staged fp32->bf16
// into LDS (register double-buffered: next chunk's loads issued before compute),
// then per owned n-block the active k-blocks (precomputed 8-bit masks in LDS)
// are consumed in PAIRS via mfma_f32_16x16x32_bf16. Odd tail uses a permanently
// zeroed 9th LDS slot as the A second-half (A=0 => contribution 0).
// x raw traffic = M*K*4 * (N/CCOLS) = 536 MB guaranteed (vs ~2.4 GB fetched
// by cache-reliant n-block-per-wg structure).
// Grid (4, 512): linear id = nc + 4*mt -> XCD = nc + 4*(mt&1), so each XCD
// serves a single n-chunk: its active W (~1.7 MB) + mask head-rows stay in L2.
// ---------------------------------------------------------------------------
__global__ __launch_bounds__(256) void bsl_gemm(
        const float* __restrict__ x,
        const float* __restrict__ w,
        const float* __restrict__ bias,
        const unsigned char* __restrict__ mask,
        float* __restrict__ out) {
    // xs: 8 staged slots (cols 0..127) + zero slot (cols 128..143), stride 152
    // halves => row stride 304 B (16B-aligned reads, banks spread via *76 mod 32).
    __shared__ __hip_bfloat16 xs[BM][152];
    __shared__ unsigned char  nbm[NCH][64];   // [chunk][n-block] active-kb bits

    const int nc   = blockIdx.x;          // n-chunk 0..3
    const int m0   = blockIdx.y * BM;     // m base
    const int t    = threadIdx.x;
    const int wq   = t >> 6;              // wave = n-quarter
    const int lane = t & 63;
    const int q    = lane >> 4;
    const int rl   = lane & 15;

    // --- issue chunk-0 x prefetch first (latency hides under mask scan) ---
    const int srow = t >> 4;              // 0..15
    const int sseg = t & 15;              // 0..15 (8 floats each)
    const float* xrow = x + (size_t)(m0 + srow) * K_TOT + sseg * 8;
    float4 p0 = ((const float4*)xrow)[0];
    float4 p1 = ((const float4*)xrow)[1];

    // --- zero slot (never overwritten; A-operand for odd tails) ---
    if (t < BM) {
        *(uint4*)&xs[t][128] = make_uint4(0, 0, 0, 0);
        *(uint4*)&xs[t][136] = make_uint4(0, 0, 0, 0);
    }

    // --- build per-(chunk, n-block) 8-bit active masks (block head elements) ---
    {
        const int flags = g_flags;
        const int nb  = t >> 2;            // 0..63
        const int chb = (t & 3) * 8;       // 8 consecutive chunks per thread
        const size_t rowe = (size_t)(nc * CCOLS + nb * 16) * K_TOT;
        #pragma unroll
        for (int p = 0; p < 8; ++p) {
            const int ch = chb + p;
            unsigned int bb = 0;
            #pragma unroll
            for (int i = 0; i < 8; ++i) {
                const size_t e = rowe + (size_t)(ch * 8 + i) * 16;
                unsigned int v;
                if (flags & 1)      v = mask[e];
                else if (flags & 2) v = ((const unsigned short*)mask)[e];
                else                v = ((const unsigned int*)mask)[e];
                bb |= (unsigned int)(v != 0u) << i;
            }
            nbm[ch][nb] = (unsigned char)bb;
        }
    }
    __syncthreads();

    f32x4 acc[16];
    #pragma unroll
    for (int i = 0; i < 16; ++i) acc[i] = (f32x4){0.f, 0.f, 0.f, 0.f};

    // W base for this wave's n-quarter: row (nc*1024 + wq*256 + rl)
    const float* wbase = w + (size_t)(nc * CCOLS + wq * 256 + rl) * K_TOT;

    for (int ch = 0; ch < NCH; ++ch) {
        // ---- stage current chunk; issue next chunk's loads early ----
        float4 c0 = p0, c1 = p1;
        if (ch + 1 < NCH) {
            const float* nx = xrow + (ch + 1) * 128;
            p0 = ((const float4*)nx)[0];
            p1 = ((const float4*)nx)[1];
        }
        {
            union { __hip_bfloat16 h[8]; uint4 u; } cv;
            const float ff[8] = {c0.x, c0.y, c0.z, c0.w, c1.x, c1.y, c1.z, c1.w};
            #pragma unroll
            for (int e = 0; e < 8; ++e) cv.h[e] = __float2bfloat16(ff[e]);
            *(uint4*)&xs[srow][sseg * 8] = cv.u;
        }
        __syncthreads();

        // wave's 16 activity bytes for this chunk (one uniform 16B LDS read)
        const uint4 mm = *(const uint4*)&nbm[ch][wq * 16];
        const unsigned int mw[4] = {mm.x, mm.y, mm.z, mm.w};

        #pragma unroll
        for (int nbl = 0; nbl < 16; ++nbl) {
            unsigned int b = (mw[nbl >> 2] >> ((nbl & 3) * 8)) & 0xffu;
            if (!b) continue;
            const float* wp = wbase + (size_t)nbl * (16 * K_TOT) + ch * 128;
            do {
                const int i1 = __builtin_ctz(b); b &= b - 1u;
                int i2, kw2;
                if (b) { i2 = __builtin_ctz(b); b &= b - 1u; kw2 = i2; }
                else   { i2 = 8;                             kw2 = i1; }  // zero slot
                const int ia = (q < 2) ? i1 : i2;   // A slot (k 0..15 vs 16..31)
                const int iw = (q < 2) ? i1 : kw2;  // W k-block (valid addr on tail)
                bf16x8 a = *(const bf16x8*)&xs[rl][ia * 16 + (q & 1) * 8];
                const float4* wv = (const float4*)(wp + iw * 16 + (q & 1) * 8);
                float4 f0 = wv[0], f1 = wv[1];
                union { __hip_bfloat16 h[8]; bf16x8 v; } cb;
                const float gg[8] = {f0.x, f0.y, f0.z, f0.w, f1.x, f1.y, f1.z, f1.w};
                #pragma unroll
                for (int e = 0; e < 8; ++e) cb.h[e] = __float2bfloat16(gg[e]);
                acc[nbl] = __builtin_amdgcn_mfma_f32_16x16x32_bf16(a, cb.v, acc[nbl], 0, 0, 0);
            } while (b);
        }
        __syncthreads();
    }

    // ---- epilogue: C/D layout col=lane&15, row=q*4+reg ----
    #pragma unroll
    for (int nbl = 0; nbl < 16; ++nbl) {
        const int col = nc * CCOLS + (wq * 16 + nbl) * 16 + rl;
        const float bv = bias[col];
        #pragma unroll
        for (int rg = 0; rg < 4; ++rg) {
            out[(size_t)(m0 + q * 4 + rg) * N_TOT + col] = acc[nbl][rg] + bv;
        }
    }
}

extern "C" void kernel_launch(void* const* d_in, const int* in_sizes, int n_in,
                              void* d_out, int out_size, void* d_ws, size_t ws_size,
                              hipStream_t stream) {
    const float* x    = (const float*)d_in[0];
    const float* w    = (const float*)d_in[1];
    const float* bias = (const float*)d_in[2];
    const unsigned char* mask = (const unsigned char*)d_in[3];
    float* out = (float*)d_out;

    bsl_detect<<<1, 256, 0, stream>>>(mask);

    dim3 grid(N_TOT / CCOLS, M_TOT / BM);   // (4, 512): n-chunk pinned per XCD
    bsl_gemm<<<grid, 256, 0, stream>>>(x, w, bias, mask, out);
}